// Round 1
// baseline (1196.728 us; speedup 1.0000x reference)
//
#include <hip/hip_runtime.h>
#include <hip/hip_bf16.h>

#define NN 100000
#define NEG 1600000
#define DD 256
#define DOUT 128

typedef unsigned short u16;
typedef unsigned int u32;
typedef __attribute__((ext_vector_type(8))) __bf16 bf16x8;
typedef __attribute__((ext_vector_type(4))) float f32x4;

__device__ __forceinline__ float b2f(u16 b){ u32 u=((u32)b)<<16; float f; __builtin_memcpy(&f,&u,4); return f; }
__device__ __forceinline__ u16 f2b(float f){ u32 u; __builtin_memcpy(&u,&f,4); u32 r=(u + 0x7FFFu + ((u>>16)&1u))>>16; return (u16)r; }
__device__ __forceinline__ u32 pack2(float a, float b){ return (u32)f2b(a) | ((u32)f2b(b)<<16); }

// ---------------- weight transpose (fp32 [256][ncols] -> bf16 [ncols][256]) ----------------
__global__ void k_wtrans(const float* __restrict__ W, u16* __restrict__ WT, int ncols){
  int n = blockIdx.x; int k = threadIdx.x;
  WT[n*DD + k] = f2b(W[k*ncols + n]);
}

// ---------------- graph prep ----------------
__global__ void k_deg(const int* __restrict__ ei, int* __restrict__ deg){
  int e = blockIdx.x*256 + threadIdx.x;
  if(e < NEG) atomicAdd(&deg[ei[NEG + e]], 1);
}

__global__ void k_scan_a(const int* __restrict__ deg, int* __restrict__ part){
  __shared__ int s[256];
  int i = blockIdx.x*256 + threadIdx.x;
  int v = (i < NN) ? deg[i] : 0;
  s[threadIdx.x] = v; __syncthreads();
  for(int o=128;o>0;o>>=1){ if(threadIdx.x<o) s[threadIdx.x]+=s[threadIdx.x+o]; __syncthreads(); }
  if(threadIdx.x==0) part[blockIdx.x]=s[0];
}

__global__ void k_scan_b(int* __restrict__ part){
  __shared__ int s[512];
  int tx = threadIdx.x;
  int v = (tx < 391) ? part[tx] : 0;
  s[tx] = v; __syncthreads();
  for(int o=1;o<512;o<<=1){ int t=(tx>=o)?s[tx-o]:0; __syncthreads(); s[tx]+=t; __syncthreads(); }
  if(tx < 391) part[tx] = s[tx]-v;  // exclusive
}

__global__ void k_scan_c(const int* __restrict__ deg, const int* __restrict__ part,
                         int* __restrict__ rowstart, int* __restrict__ cursor, float* __restrict__ dsq){
  __shared__ int s[256];
  int tx = threadIdx.x;
  int i = blockIdx.x*256 + tx;
  int v = (i < NN) ? deg[i] : 0;
  s[tx]=v; __syncthreads();
  for(int o=1;o<256;o<<=1){ int t=(tx>=o)?s[tx-o]:0; __syncthreads(); s[tx]+=t; __syncthreads(); }
  int incl = s[tx];
  int base = part[blockIdx.x];
  if(i < NN){
    int excl = base + incl - v;
    rowstart[i]=excl; cursor[i]=excl;
    dsq[i] = (v>0) ? rsqrtf((float)v) : 0.f;
    if(i == NN-1) rowstart[NN] = base + incl;
  }
}

__global__ void k_csr(const int* __restrict__ ei, int* __restrict__ cursor, int* __restrict__ csr_row){
  int e = blockIdx.x*256 + threadIdx.x;
  if(e < NEG){
    int r = ei[e], c = ei[NEG + e];
    int p = atomicAdd(&cursor[c], 1);
    csr_row[p] = r;
  }
}

// ---------------- BN helpers ----------------
__global__ void k_bnprep(const float* __restrict__ cs, const float* __restrict__ cq,
                         const float* __restrict__ g, const float* __restrict__ b,
                         float* __restrict__ scale, float* __restrict__ shift){
  int c = threadIdx.x;
  float m = cs[c] * (1.0f/NN);
  float var = cq[c] * (1.0f/NN) - m*m;
  float rs = rsqrtf(var + 1e-5f);
  float sc = g[c]*rs;
  scale[c] = sc; shift[c] = b[c] - m*sc;
}

__global__ void k_bnrelu(const u16* __restrict__ yg, const float* __restrict__ scale,
                         const float* __restrict__ shift, u16* __restrict__ g0){
  long long i = (long long)(blockIdx.x*256 + threadIdx.x) * 8;
  if(i >= (long long)NN*DD) return;
  int c0 = (int)(i & 255);
  uint4 v = *(const uint4*)&yg[i];
  const u16* p = (const u16*)&v;
  u32 w[4];
  #pragma unroll
  for(int j=0;j<4;j++){
    float a = fmaxf(b2f(p[2*j  ])*scale[c0+2*j  ]+shift[c0+2*j  ], 0.f);
    float b_ = fmaxf(b2f(p[2*j+1])*scale[c0+2*j+1]+shift[c0+2*j+1], 0.f);
    w[j] = pack2(a,b_);
  }
  uint4 sv; sv.x=w[0]; sv.y=w[1]; sv.z=w[2]; sv.w=w[3];
  *(uint4*)&g0[i] = sv;
}

// ---------------- CSR gather: agg[i] = sum_e dsq[i]*dsq[row]*g0[row] ----------------
__global__ __launch_bounds__(256) void k_gather(const u16* __restrict__ g0, const int* __restrict__ rowstart,
                                                const int* __restrict__ csr_row, const float* __restrict__ dsq,
                                                u16* __restrict__ agg){
  int node = blockIdx.x*8 + (threadIdx.x>>5);
  int lane = threadIdx.x & 31;
  if(node >= NN) return;
  int s = rowstart[node], e = rowstart[node+1];
  float di = dsq[node];
  int d0 = lane*8;
  float acc[8] = {0,0,0,0,0,0,0,0};
  int j = s;
  for(; j+1 < e; j += 2){
    int r0 = csr_row[j], r1 = csr_row[j+1];
    float w0 = di*dsq[r0], w1 = di*dsq[r1];
    uint4 a = *(const uint4*)&g0[(size_t)r0*DD + d0];
    uint4 b = *(const uint4*)&g0[(size_t)r1*DD + d0];
    const u16* pa = (const u16*)&a; const u16* pb = (const u16*)&b;
    #pragma unroll
    for(int t=0;t<8;t++){ acc[t] += w0*b2f(pa[t]); acc[t] += w1*b2f(pb[t]); }
  }
  if(j < e){
    int r0 = csr_row[j]; float w0 = di*dsq[r0];
    uint4 a = *(const uint4*)&g0[(size_t)r0*DD + d0];
    const u16* pa = (const u16*)&a;
    #pragma unroll
    for(int t=0;t<8;t++) acc[t] += w0*b2f(pa[t]);
  }
  u32 w[4];
  #pragma unroll
  for(int t=0;t<4;t++) w[t] = pack2(acc[2*t], acc[2*t+1]);
  uint4 sv; sv.x=w[0]; sv.y=w[1]; sv.z=w[2]; sv.w=w[3];
  *(uint4*)&agg[(size_t)node*DD + d0] = sv;
}

// ---------------- generic fused MFMA GEMM ----------------
// EP: 0=LN+relu(h)  1=row-L2-norm(q)  2=rownorm+transposed+colsum(kT)  3=plain transposed+colsum(vT)
//     4=store+colstats(yg,y2)  5=attention(num/denom + LN + relu -> x1)  6=final combine->out  7=split-K kvs atomic
enum { EP_LN=0, EP_QN=1, EP_KT=2, EP_VT=3, EP_CS=4, EP_AT=5, EP_OUTP=6, EP_KV=7 };

template<int EP, bool AF32, int NCOLS>
__global__ __launch_bounds__(256,2)
void k_gemm(const void* __restrict__ Ap, const u16* __restrict__ BT,
            const float* __restrict__ bias,
            u16* __restrict__ outb, float* __restrict__ outf,
            const float* __restrict__ p0, const float* __restrict__ p1,
            const float* __restrict__ p2, const float* __restrict__ p3,
            const u16* __restrict__ hb, const u16* __restrict__ x1b, const u16* __restrict__ g0b,
            float* __restrict__ st0, float* __restrict__ st1,
            int kSteps, int kLimit, int Astride, int Bstride, int Mlim)
{
  constexpr int NT = NCOLS/64;
  constexpr int TSR = (EP==EP_KT||EP==EP_VT) ? 64 : 1;
  constexpr int NRED = (EP==EP_LN||EP==EP_AT) ? 2 : 1;
  const int tid = threadIdx.x;
  const int wave = tid>>6, lane = tid&63, quad = lane>>4, l15 = lane&15;
  const int m0 = blockIdx.x*64;
  const int kBase = blockIdx.y*(kSteps*32);
  const int wb = wave*(NCOLS/4);

  __shared__ __align__(16) u16 As[64][48];
  __shared__ __align__(16) u16 Bs[NCOLS][48];
  __shared__ u16 Ts[TSR][DD+2];
  __shared__ float red[NRED][4][64];
  __shared__ float dls[64];

  f32x4 acc[4][NT];
  #pragma unroll
  for(int i=0;i<4;i++)
    #pragma unroll
    for(int j=0;j<NT;j++){ acc[i][j][0]=0.f; acc[i][j][1]=0.f; acc[i][j][2]=0.f; acc[i][j][3]=0.f; }
  float dot[4] = {0.f,0.f,0.f,0.f};

  for(int st=0; st<kSteps; st++){
    const int k0 = kBase + st*32;
    __syncthreads();
    // ---- stage A tile [64][32] ----
    if constexpr (EP==EP_OUTP){
      const u16* y2p = (const u16*)Ap;
      int row=tid>>2, seg=tid&3, gr=m0+row, gk=k0+seg*8;
      u32 w[4]={0,0,0,0};
      if(gr<Mlim){
        uint4 vy = *(const uint4*)&y2p[(size_t)gr*DD+gk];
        uint4 vx = *(const uint4*)&x1b[(size_t)gr*DD+gk];
        uint4 vg = *(const uint4*)&g0b[(size_t)gr*DD+gk];
        const u16* py=(const u16*)&vy; const u16* px=(const u16*)&vx; const u16* pg=(const u16*)&vg;
        float f[8];
        #pragma unroll
        for(int j=0;j<8;j++){
          int kk=gk+j;
          float x2v = fmaxf(p0[kk]*b2f(py[j])+p1[kk], 0.f) + b2f(pg[j]);
          f[j] = 0.8f*x2v + 0.2f*b2f(px[j]);
        }
        #pragma unroll
        for(int j=0;j<4;j++) w[j]=pack2(f[2*j],f[2*j+1]);
      }
      uint4 sv; sv.x=w[0]; sv.y=w[1]; sv.z=w[2]; sv.w=w[3];
      *(uint4*)&As[row][seg*8] = sv;
    } else if constexpr (AF32){
      const float* Af = (const float*)Ap;
      #pragma unroll
      for(int it=0; it<2; it++){
        int s=tid+it*256, row=s>>3, seg=s&7, gr=m0+row, gk=k0+seg*4;
        uint2 sv; sv.x=0u; sv.y=0u;
        if(gr<Mlim && gk<kLimit){
          float4 v = *(const float4*)&Af[(size_t)gr*Astride+gk];
          sv.x = pack2(v.x,v.y); sv.y = pack2(v.z,v.w);
        }
        *(uint2*)&As[row][seg*4] = sv;
      }
    } else {
      const u16* Ab = (const u16*)Ap;
      int row=tid>>2, seg=tid&3, gr=m0+row, gk=k0+seg*8;
      uint4 v = make_uint4(0u,0u,0u,0u);
      if(gr<Mlim && gk<kLimit) v = *(const uint4*)&Ab[(size_t)gr*Astride+gk];
      *(uint4*)&As[row][seg*8] = v;
    }
    // ---- stage B tile [NCOLS][32] (BT layout: [n][k]) ----
    #pragma unroll
    for(int it=0; it<NCOLS/64; it++){
      int s=tid+it*256, row=s>>2, seg=s&3, gk=k0+seg*8;
      uint4 v = make_uint4(0u,0u,0u,0u);
      if(gk<kLimit) v = *(const uint4*)&BT[(size_t)row*Bstride+gk];
      *(uint4*)&Bs[row][seg*8] = v;
    }
    __syncthreads();
    // ---- fragments + MFMA ----
    uint4 afu[4]; uint4 bfu[NT];
    #pragma unroll
    for(int mi=0;mi<4;mi++) afu[mi] = *(const uint4*)&As[mi*16+l15][quad*8];
    #pragma unroll
    for(int ni=0;ni<NT;ni++) bfu[ni] = *(const uint4*)&Bs[wb+ni*16+l15][quad*8];
    if constexpr (EP==EP_AT){
      #pragma unroll
      for(int mi=0;mi<4;mi++){
        const u16* ap = (const u16*)&afu[mi];
        #pragma unroll
        for(int j=0;j<8;j++) dot[mi] += b2f(ap[j]) * p2[k0 + quad*8 + j];
      }
    }
    #pragma unroll
    for(int mi=0;mi<4;mi++)
      #pragma unroll
      for(int ni=0;ni<NT;ni++)
        acc[mi][ni] = __builtin_amdgcn_mfma_f32_16x16x32_bf16(
            __builtin_bit_cast(bf16x8, afu[mi]),
            __builtin_bit_cast(bf16x8, bfu[ni]),
            acc[mi][ni], 0,0,0);
  }

  int colg[NT]; float bv[NT];
  #pragma unroll
  for(int ni=0;ni<NT;ni++){ colg[ni] = wb + ni*16 + l15; bv[ni] = bias ? bias[colg[ni]] : 0.f; }

  if constexpr (EP==EP_KV){
    #pragma unroll
    for(int mi=0;mi<4;mi++)
      #pragma unroll
      for(int r=0;r<4;r++){
        int gr = m0 + mi*16 + quad*4 + r;
        if(gr<Mlim){
          #pragma unroll
          for(int ni=0;ni<NT;ni++) atomicAdd(&outf[(size_t)gr*DD + colg[ni]], acc[mi][ni][r]);
        }
      }
    return;
  }
  if constexpr (EP==EP_OUTP){
    #pragma unroll
    for(int mi=0;mi<4;mi++)
      #pragma unroll
      for(int r=0;r<4;r++){
        int gr = m0 + mi*16 + quad*4 + r;
        if(gr<Mlim){
          #pragma unroll
          for(int ni=0;ni<NT;ni++) outf[(size_t)gr*DOUT + colg[ni]] = acc[mi][ni][r] + bv[ni];
        }
      }
    return;
  }
  if constexpr (EP==EP_CS){
    float cs[NT], cq[NT];
    #pragma unroll
    for(int ni=0;ni<NT;ni++){ cs[ni]=0.f; cq[ni]=0.f; }
    #pragma unroll
    for(int mi=0;mi<4;mi++)
      #pragma unroll
      for(int r=0;r<4;r++){
        int gr = m0 + mi*16 + quad*4 + r;
        if(gr<Mlim){
          #pragma unroll
          for(int ni=0;ni<NT;ni++){
            float v = acc[mi][ni][r] + bv[ni];
            outb[(size_t)gr*DD + colg[ni]] = f2b(v);
            cs[ni]+=v; cq[ni]+=v*v;
          }
        }
      }
    #pragma unroll
    for(int ni=0;ni<NT;ni++){
      float c=cs[ni], q=cq[ni];
      c += __shfl_xor(c,16); c += __shfl_xor(c,32);
      q += __shfl_xor(q,16); q += __shfl_xor(q,32);
      if(quad==0){ atomicAdd(&st0[colg[ni]], c); atomicAdd(&st1[colg[ni]], q); }
    }
    return;
  }
  if constexpr (EP==EP_QN || EP==EP_KT || EP==EP_VT){
    float rsr[4][4];
    if constexpr (EP!=EP_VT){
      #pragma unroll
      for(int mi=0;mi<4;mi++)
        #pragma unroll
        for(int r=0;r<4;r++){
          float s2=0.f;
          #pragma unroll
          for(int ni=0;ni<NT;ni++){ float v=acc[mi][ni][r]+bv[ni]; s2+=v*v; }
          for(int o=1;o<16;o<<=1) s2 += __shfl_xor(s2,o);
          if(l15==0) red[0][wave][mi*16+quad*4+r] = s2;
        }
      __syncthreads();
      #pragma unroll
      for(int mi=0;mi<4;mi++)
        #pragma unroll
        for(int r=0;r<4;r++){
          int row = mi*16+quad*4+r;
          float S2 = red[0][0][row]+red[0][1][row]+red[0][2][row]+red[0][3][row];
          rsr[mi][r] = rsqrtf(S2);
        }
    } else {
      #pragma unroll
      for(int mi=0;mi<4;mi++)
        #pragma unroll
        for(int r=0;r<4;r++) rsr[mi][r]=1.f;
    }
    if constexpr (EP==EP_QN){
      #pragma unroll
      for(int mi=0;mi<4;mi++)
        #pragma unroll
        for(int r=0;r<4;r++){
          int gr = m0 + mi*16+quad*4+r;
          if(gr<Mlim){
            #pragma unroll
            for(int ni=0;ni<NT;ni++)
              outb[(size_t)gr*DD + colg[ni]] = f2b((acc[mi][ni][r]+bv[ni])*rsr[mi][r]);
          }
        }
      return;
    } else {
      float cs[NT];
      #pragma unroll
      for(int ni=0;ni<NT;ni++) cs[ni]=0.f;
      #pragma unroll
      for(int mi=0;mi<4;mi++)
        #pragma unroll
        for(int r=0;r<4;r++){
          int row = mi*16+quad*4+r;
          int gr = m0 + row;
          #pragma unroll
          for(int ni=0;ni<NT;ni++){
            float v = (gr<Mlim) ? (acc[mi][ni][r]+bv[ni])*rsr[mi][r] : 0.f;
            cs[ni] += v;
            Ts[row][colg[ni]] = f2b(v);
          }
        }
      #pragma unroll
      for(int ni=0;ni<NT;ni++){
        float c=cs[ni];
        c += __shfl_xor(c,16); c += __shfl_xor(c,32);
        if(quad==0) atomicAdd(&st0[colg[ni]], c);
      }
      __syncthreads();
      for(int dd=0;dd<64;dd++){
        int d = wb + dd;
        int gn = m0 + lane;
        if(gn<Mlim) outb[(size_t)d*NN + gn] = Ts[lane][d];
      }
      return;
    }
  }
  if constexpr (EP==EP_AT){
    #pragma unroll
    for(int mi=0;mi<4;mi++){
      float ds = dot[mi];
      ds += __shfl_xor(ds,16); ds += __shfl_xor(ds,32);
      if(wave==0) dls[mi*16+l15] = ds + 200000.0f;   // + 2*nf
    }
    __syncthreads();
    float vs[NT];
    #pragma unroll
    for(int ni=0;ni<NT;ni++) vs[ni] = p3[colg[ni]];
    #pragma unroll
    for(int mi=0;mi<4;mi++)
      #pragma unroll
      for(int r=0;r<4;r++){
        int row = mi*16+quad*4+r;
        int gr = m0 + row;
        float den = dls[row];
        #pragma unroll
        for(int ni=0;ni<NT;ni++){
          float num = acc[mi][ni][r] + 100000.0f*vs[ni];
          float hv = (gr<Mlim) ? b2f(hb[(size_t)gr*DD + colg[ni]]) : 0.f;
          acc[mi][ni][r] = (num/den + hv)*0.5f;
        }
      }
  }
  if constexpr (EP==EP_LN || EP==EP_AT){
    #pragma unroll
    for(int mi=0;mi<4;mi++)
      #pragma unroll
      for(int r=0;r<4;r++){
        float s=0.f, s2=0.f;
        #pragma unroll
        for(int ni=0;ni<NT;ni++){ float v=acc[mi][ni][r]+bv[ni]; s+=v; s2+=v*v; }
        for(int o=1;o<16;o<<=1){ s += __shfl_xor(s,o); s2 += __shfl_xor(s2,o); }
        if(l15==0){ int row=mi*16+quad*4+r; red[0][wave][row]=s; red[1][wave][row]=s2; }
      }
    __syncthreads();
    float gcol[NT], bcol[NT];
    #pragma unroll
    for(int ni=0;ni<NT;ni++){ gcol[ni]=p0[colg[ni]]; bcol[ni]=p1[colg[ni]]; }
    #pragma unroll
    for(int mi=0;mi<4;mi++)
      #pragma unroll
      for(int r=0;r<4;r++){
        int row = mi*16+quad*4+r;
        int gr = m0 + row;
        if(gr<Mlim){
          float S  = red[0][0][row]+red[0][1][row]+red[0][2][row]+red[0][3][row];
          float S2 = red[1][0][row]+red[1][1][row]+red[1][2][row]+red[1][3][row];
          float mean = S*(1.0f/DD);
          float var  = S2*(1.0f/DD) - mean*mean;
          float rstd = rsqrtf(var + 1e-5f);
          #pragma unroll
          for(int ni=0;ni<NT;ni++){
            float v = acc[mi][ni][r]+bv[ni];
            v = (v-mean)*rstd*gcol[ni] + bcol[ni];
            outb[(size_t)gr*DD + colg[ni]] = f2b(fmaxf(v,0.f));
          }
        }
      }
  }
}

// ---------------- launch ----------------
extern "C" void kernel_launch(void* const* d_in, const int* in_sizes, int n_in,
                              void* d_out, int out_size, void* d_ws, size_t ws_size,
                              hipStream_t stream) {
  (void)in_sizes; (void)n_in; (void)out_size; (void)ws_size;
  const float* x     = (const float*)d_in[0];
  const int*   ei    = (const int*)d_in[1];
  const float* tW0   = (const float*)d_in[2];
  const float* tb0   = (const float*)d_in[3];
  const float* tln0g = (const float*)d_in[4];
  const float* tln0b = (const float*)d_in[5];
  const float* Wq    = (const float*)d_in[6];
  const float* bq    = (const float*)d_in[7];
  const float* Wk    = (const float*)d_in[8];
  const float* bk    = (const float*)d_in[9];
  const float* Wv    = (const float*)d_in[10];
  const float* bvv   = (const float*)d_in[11];
  const float* tln1g = (const float*)d_in[12];
  const float* tln1b = (const float*)d_in[13];
  const float* gW0   = (const float*)d_in[14];
  const float* gb0   = (const float*)d_in[15];
  const float* gbn0g = (const float*)d_in[16];
  const float* gbn0b = (const float*)d_in[17];
  const float* gWc   = (const float*)d_in[18];
  const float* gbc   = (const float*)d_in[19];
  const float* gbn1g = (const float*)d_in[20];
  const float* gbn1b = (const float*)d_in[21];
  const float* Wo    = (const float*)d_in[22];
  const float* bo    = (const float*)d_in[23];

  char* ws = (char*)d_ws;
  size_t off = 0;
  auto give = [&](size_t b){ size_t o = off; off += (b + 511) & ~(size_t)511; return o; };
  const size_t NB = (size_t)NN*DD*2;   // 51.2 MB bf16 buffer
  size_t o_b0=give(NB), o_b1=give(NB), o_b2=give(NB), o_b3=give(NB), o_b4=give(NB);
  size_t o_csr = give((size_t)NEG*4);
  size_t o_rowstart = give((NN+1)*4);
  size_t o_cursor   = give(NN*4);
  size_t o_dsq      = give(NN*4);
  size_t o_part     = give(512*4);
  size_t o_wt0=give(DD*DD*2), o_wq=give(DD*DD*2), o_wk=give(DD*DD*2), o_wv=give(DD*DD*2);
  size_t o_wg0=give(DD*DD*2), o_wgc=give(DD*DD*2), o_wo=give(DD*DOUT*2);
  size_t o_kvsT=give(DD*DD*2);
  size_t o_sc0=give(DD*4), o_sh0=give(DD*4), o_sc1=give(DD*4), o_sh1=give(DD*4);
  // zero region (contiguous): deg, kvs, ksum, vsum, cs0, cq0, cs1, cq1
  size_t o_zero = off;
  size_t o_deg = give(NN*4);
  size_t o_kvs = give(DD*DD*4);
  size_t o_ksum=give(DD*4), o_vsum=give(DD*4);
  size_t o_cs0=give(DD*4), o_cq0=give(DD*4), o_cs1=give(DD*4), o_cq1=give(DD*4);
  size_t zero_len = off - o_zero;

  u16* B0=(u16*)(ws+o_b0); u16* B1=(u16*)(ws+o_b1); u16* B2=(u16*)(ws+o_b2);
  u16* B3=(u16*)(ws+o_b3); u16* B4=(u16*)(ws+o_b4);
  int* csr=(int*)(ws+o_csr); int* rowstart=(int*)(ws+o_rowstart); int* cursor=(int*)(ws+o_cursor);
  float* dsq=(float*)(ws+o_dsq); int* part=(int*)(ws+o_part);
  u16* wt0=(u16*)(ws+o_wt0); u16* wq=(u16*)(ws+o_wq); u16* wk=(u16*)(ws+o_wk); u16* wv=(u16*)(ws+o_wv);
  u16* wg0=(u16*)(ws+o_wg0); u16* wgc=(u16*)(ws+o_wgc); u16* wo=(u16*)(ws+o_wo);
  u16* kvsT=(u16*)(ws+o_kvsT);
  float* sc0=(float*)(ws+o_sc0); float* sh0=(float*)(ws+o_sh0);
  float* sc1=(float*)(ws+o_sc1); float* sh1=(float*)(ws+o_sh1);
  int* deg=(int*)(ws+o_deg); float* kvs=(float*)(ws+o_kvs);
  float* ksum=(float*)(ws+o_ksum); float* vsum=(float*)(ws+o_vsum);
  float* cs0=(float*)(ws+o_cs0); float* cq0=(float*)(ws+o_cq0);
  float* cs1=(float*)(ws+o_cs1); float* cq1=(float*)(ws+o_cq1);

  hipMemsetAsync(ws + o_zero, 0, zero_len, stream);

  // weights -> transposed bf16
  k_wtrans<<<256,256,0,stream>>>(tW0, wt0, 256);
  k_wtrans<<<256,256,0,stream>>>(Wq,  wq,  256);
  k_wtrans<<<256,256,0,stream>>>(Wk,  wk,  256);
  k_wtrans<<<256,256,0,stream>>>(Wv,  wv,  256);
  k_wtrans<<<256,256,0,stream>>>(gW0, wg0, 256);
  k_wtrans<<<256,256,0,stream>>>(gWc, wgc, 256);
  k_wtrans<<<128,256,0,stream>>>(Wo,  wo,  128);

  // graph CSR
  k_deg<<<6250,256,0,stream>>>(ei, deg);
  k_scan_a<<<391,256,0,stream>>>(deg, part);
  k_scan_b<<<1,512,0,stream>>>(part);
  k_scan_c<<<391,256,0,stream>>>(deg, part, rowstart, cursor, dsq);
  k_csr<<<6250,256,0,stream>>>(ei, cursor, csr);

  const int MG = 1563;  // ceil(100000/64)
  // h = relu(LN(x@tW0+tb0))
  k_gemm<EP_LN,true,256><<<dim3(MG,1),256,0,stream>>>(x, wt0, tb0, B0, nullptr,
      tln0g, tln0b, nullptr, nullptr, nullptr, nullptr, nullptr, nullptr, nullptr,
      8, 256, 256, 256, NN);
  // yg = x@gW0+gb0 (+colstats)
  k_gemm<EP_CS,true,256><<<dim3(MG,1),256,0,stream>>>(x, wg0, gb0, B1, nullptr,
      nullptr, nullptr, nullptr, nullptr, nullptr, nullptr, nullptr, cs0, cq0,
      8, 256, 256, 256, NN);
  // q = rownorm(h@Wq+bq)
  k_gemm<EP_QN,false,256><<<dim3(MG,1),256,0,stream>>>(B0, wq, bq, B2, nullptr,
      nullptr, nullptr, nullptr, nullptr, nullptr, nullptr, nullptr, nullptr, nullptr,
      8, 256, 256, 256, NN);
  // kT = rownorm(h@Wk+bk)^T  (+ksum)
  k_gemm<EP_KT,false,256><<<dim3(MG,1),256,0,stream>>>(B0, wk, bk, B3, nullptr,
      nullptr, nullptr, nullptr, nullptr, nullptr, nullptr, nullptr, ksum, nullptr,
      8, 256, 256, 256, NN);
  // vT = (h@Wv+bv)^T  (+vsum)
  k_gemm<EP_VT,false,256><<<dim3(MG,1),256,0,stream>>>(B0, wv, bvv, B4, nullptr,
      nullptr, nullptr, nullptr, nullptr, nullptr, nullptr, nullptr, vsum, nullptr,
      8, 256, 256, 256, NN);
  // kvs = k^T @ v  (split-K atomic fp32)
  k_gemm<EP_KV,false,256><<<dim3(4,98),256,0,stream>>>(B3, B4, nullptr, nullptr, kvs,
      nullptr, nullptr, nullptr, nullptr, nullptr, nullptr, nullptr, nullptr, nullptr,
      32, NN, NN, NN, 256);
  k_wtrans<<<256,256,0,stream>>>(kvs, kvsT, 256);
  // BN0 -> g0
  k_bnprep<<<1,256,0,stream>>>(cs0, cq0, gbn0g, gbn0b, sc0, sh0);
  k_bnrelu<<<12500,256,0,stream>>>(B1, sc0, sh0, B3 /*reuse: g0*/);
  // wait: B3 held kT, consumed by kvs above -> safe to reuse as g0
  k_gather<<<12500,256,0,stream>>>(B3, rowstart, csr, dsq, B1 /*agg (yg dead)*/);
  // y2 = agg@gWc+gbc (+colstats)
  k_gemm<EP_CS,false,256><<<dim3(MG,1),256,0,stream>>>(B1, wgc, gbc, B4 /*y2 (vT dead)*/, nullptr,
      nullptr, nullptr, nullptr, nullptr, nullptr, nullptr, nullptr, cs1, cq1,
      8, 256, 256, 256, NN);
  k_bnprep<<<1,256,0,stream>>>(cs1, cq1, gbn1g, gbn1b, sc1, sh1);
  // x1 = relu(LN(( (q@kvs + nf*vsum)/(q@ksum+2nf) + h)/2))
  k_gemm<EP_AT,false,256><<<dim3(MG,1),256,0,stream>>>(B2, kvsT, nullptr, B1 /*x1 (agg dead)*/, nullptr,
      tln1g, tln1b, ksum, vsum, B0 /*h*/, nullptr, nullptr, nullptr, nullptr,
      8, 256, 256, 256, NN);
  // out = (0.8*(relu(bn1(y2))+g0) + 0.2*x1) @ Wo + bo
  k_gemm<EP_OUTP,false,128><<<dim3(MG,1),256,0,stream>>>(B4 /*y2*/, wo, bo, nullptr, (float*)d_out,
      sc1, sh1, nullptr, nullptr, nullptr, B1 /*x1*/, B3 /*g0*/, nullptr, nullptr,
      8, 256, 256, 256, NN);
}